// Round 1
// baseline (400.934 us; speedup 1.0000x reference)
//
#include <hip/hip_runtime.h>

typedef _Float16 f16;
typedef _Float16 f16x8 __attribute__((ext_vector_type(8)));
typedef float f32x4 __attribute__((ext_vector_type(4)));

#define CDIM 256
#define NPIX 9216
#define NSUB 1024
#define NB 8
#define QSTR 264
#define PSTR 1048

__device__ __forceinline__ f32x4 mfma16(f16x8 a, f16x8 b, f32x4 c) {
  return __builtin_amdgcn_mfma_f32_16x16x32_f16(a, b, c, 0, 0, 0);
}
__device__ __forceinline__ f16x8 ld8(const f16* p) { return *(const f16x8*)p; }

// ---------------- K1: fold weights, cast to f16 ----------------
__global__ void prep_weights(const float* __restrict__ Wq,
                             const float* __restrict__ Wk, const float* __restrict__ bk,
                             const float* __restrict__ Wv, const float* __restrict__ bv,
                             const float* __restrict__ Ws, const float* __restrict__ bs,
                             f16* __restrict__ WqH, f16* __restrict__ Wk2H, f16* __restrict__ Wv2H,
                             float* __restrict__ bk2, float* __restrict__ bv2) {
  int o = blockIdx.x, c = threadIdx.x;
  float ak = 0.f, av = 0.f;
  for (int i = 0; i < CDIM; ++i) {
    float w = Ws[o*CDIM + i];
    ak += w * Wk[i*CDIM + c];
    av += w * Wv[i*CDIM + c];
  }
  Wk2H[o*CDIM + c] = (f16)ak;
  Wv2H[o*CDIM + c] = (f16)av;
  WqH[o*CDIM + c]  = (f16)Wq[o*CDIM + c];
  if (c == 0) {
    float sk = 0.f, sv = 0.f;
    for (int i = 0; i < CDIM; ++i) { float w = Ws[o*CDIM + i]; sk += w*bk[i]; sv += w*bv[i]; }
    bk2[o] = sk + bs[o];
    bv2[o] = sv + bs[o];
  }
}

// ---------------- K2: x[b][c][n] f32 -> xT[b][n][c] f16 ----------------
__global__ void transpose_x(const float* __restrict__ x, f16* __restrict__ xT) {
  __shared__ f16 tile[32][34];
  int c0 = blockIdx.x * 32, n0 = blockIdx.y * 32, b = blockIdx.z;
  int tx = threadIdx.x, ty = threadIdx.y;
#pragma unroll
  for (int j = 0; j < 4; ++j) {
    int cl = ty + 8*j;
    tile[cl][tx] = (f16)x[(size_t)(b*CDIM + c0 + cl)*NPIX + n0 + tx];
  }
  __syncthreads();
#pragma unroll
  for (int j = 0; j < 4; ++j) {
    int nl = ty + 8*j;
    xT[(size_t)(b*NPIX + n0 + nl)*CDIM + c0 + tx] = tile[tx][nl];
  }
}

// ---------------- K3: kT[b][m][c], v[b][c][m] at subsampled pixels ----------------
__global__ __launch_bounds__(256) void compute_kv(
    const f16* __restrict__ xT, const f16* __restrict__ Wk2H, const f16* __restrict__ Wv2H,
    const float* __restrict__ bk2, const float* __restrict__ bv2,
    f16* __restrict__ kT, f16* __restrict__ vC) {
  int m064 = blockIdx.x * 64;
  int b = blockIdx.y;
  int tid = threadIdx.x;
  int w = tid >> 6, lane = tid & 63;
  int l15 = lane & 15, q = lane >> 4;

  const f16* xbase[4];
#pragma unroll
  for (int mt2 = 0; mt2 < 4; ++mt2) {
    int m = m064 + 16*mt2 + l15;
    int n = 288*(m >> 5) + 3*(m & 31);   // subsampled pixel index
    xbase[mt2] = xT + (size_t)(b*NPIX + n)*CDIM + 8*q;
  }
  const f16* kwb[4]; const f16* vwb[4];
#pragma unroll
  for (int t = 0; t < 4; ++t) {
    kwb[t] = Wk2H + (size_t)(64*w + 16*t + l15)*CDIM + 8*q;
    vwb[t] = Wv2H + (size_t)(64*w + 16*t + l15)*CDIM + 8*q;
  }
  f32x4 accK[4][4] = {};
  f32x4 accV[4][4] = {};
  for (int ks = 0; ks < 8; ++ks) {
    int c0 = ks * 32;
    f16x8 am[4], wk[4], wv[4];
#pragma unroll
    for (int t = 0; t < 4; ++t) {
      am[t] = ld8(xbase[t] + c0);
      wk[t] = ld8(kwb[t] + c0);
      wv[t] = ld8(vwb[t] + c0);
    }
#pragma unroll
    for (int mt2 = 0; mt2 < 4; ++mt2)
#pragma unroll
      for (int ot = 0; ot < 4; ++ot) {
        accK[mt2][ot] = mfma16(am[mt2], wk[ot], accK[mt2][ot]);   // D[m][o]
        accV[ot][mt2] = mfma16(wv[ot], am[mt2], accV[ot][mt2]);   // D[c][m]
      }
  }
#pragma unroll
  for (int mt2 = 0; mt2 < 4; ++mt2)
#pragma unroll
    for (int ot = 0; ot < 4; ++ot) {
      int o = 64*w + 16*ot + l15;
      float bo = bk2[o];
#pragma unroll
      for (int r = 0; r < 4; ++r) {
        int m = m064 + 16*mt2 + 4*q + r;
        kT[(size_t)(b*NSUB + m)*CDIM + o] = (f16)(accK[mt2][ot][r] + bo);
      }
    }
#pragma unroll
  for (int ct = 0; ct < 4; ++ct) {
    f32x4 bv4 = *(const f32x4*)(bv2 + 64*w + 16*ct + 4*q);
#pragma unroll
    for (int mt2 = 0; mt2 < 4; ++mt2) {
      int m = m064 + 16*mt2 + l15;
#pragma unroll
      for (int r = 0; r < 4; ++r) {
        int c = 64*w + 16*ct + 4*q + r;
        vC[(size_t)(b*CDIM + c)*NSUB + m] = (f16)(accV[ct][mt2][r] + bv4[r]);
      }
    }
  }
}

// ---------------- K4: fused attention ----------------
__global__ __launch_bounds__(512) void attention(
    const f16* __restrict__ xT, const f16* __restrict__ WqH, const float* __restrict__ bq,
    const f16* __restrict__ kT, const f16* __restrict__ vC,
    const float* __restrict__ x, const float* __restrict__ gamma_p,
    float* __restrict__ out) {
  __shared__ f16 shp[32 * PSTR];          // P buffer; first 32*QSTR bytes-worth aliased as q tile
  __shared__ float smax[8][32];
  __shared__ float ssum[8][32];
  f16* shq = shp;

  int bid = blockIdx.x;
  int b  = bid / (NPIX/32);
  int nt = bid % (NPIX/32);
  int n0 = nt * 32;
  int tid = threadIdx.x;
  int w = tid >> 6, lane = tid & 63;
  int l15 = lane & 15, q = lane >> 4;

  // ---- Phase A: q tile [32][256] -> LDS (wave w computes cols 32w..32w+31) ----
  {
    f32x4 acc[2][2] = {};
    const f16* xrow[2];
#pragma unroll
    for (int nt2 = 0; nt2 < 2; ++nt2)
      xrow[nt2] = xT + (size_t)(b*NPIX + n0 + 16*nt2 + l15)*CDIM + 8*q;
    const f16* wrow[2];
#pragma unroll
    for (int ot = 0; ot < 2; ++ot)
      wrow[ot] = WqH + (size_t)(32*w + 16*ot + l15)*CDIM + 8*q;
    for (int ks = 0; ks < 8; ++ks) {
      int c0 = ks * 32;
      f16x8 a0 = ld8(xrow[0] + c0), a1 = ld8(xrow[1] + c0);
      f16x8 b0 = ld8(wrow[0] + c0), b1 = ld8(wrow[1] + c0);
      acc[0][0] = mfma16(a0, b0, acc[0][0]);
      acc[0][1] = mfma16(a0, b1, acc[0][1]);
      acc[1][0] = mfma16(a1, b0, acc[1][0]);
      acc[1][1] = mfma16(a1, b1, acc[1][1]);
    }
#pragma unroll
    for (int ot = 0; ot < 2; ++ot) {
      int o = 32*w + 16*ot + l15;
      float bo = bq[o];
#pragma unroll
      for (int nt2 = 0; nt2 < 2; ++nt2)
#pragma unroll
        for (int r = 0; r < 4; ++r) {
          int nl = 16*nt2 + 4*q + r;
          shq[nl*QSTR + o] = (f16)(acc[nt2][ot][r] + bo);
        }
    }
  }
  __syncthreads();

  // ---- Phase B: S[32][128 slice] = q . k ----
  f32x4 S[2][8] = {};
  {
    const f16* kbase[8];
#pragma unroll
    for (int mt = 0; mt < 8; ++mt)
      kbase[mt] = kT + (size_t)(b*NSUB + 128*w + 16*mt + l15)*CDIM + 8*q;
    for (int ks = 0; ks < 8; ++ks) {
      int c0 = ks * 32;
      f16x8 a0 = *(const f16x8*)(shq + (l15)*QSTR + c0 + 8*q);
      f16x8 a1 = *(const f16x8*)(shq + (16 + l15)*QSTR + c0 + 8*q);
#pragma unroll
      for (int mt = 0; mt < 8; ++mt) {
        f16x8 kb = ld8(kbase[mt] + c0);
        S[0][mt] = mfma16(a0, kb, S[0][mt]);
        S[1][mt] = mfma16(a1, kb, S[1][mt]);
      }
    }
  }

  // ---- Phase C: softmax over m (rows owned per lane-quarter) ----
  float M[2][4], inv[2][4];
  {
    float mx[2][4];
#pragma unroll
    for (int nt2 = 0; nt2 < 2; ++nt2)
#pragma unroll
      for (int r = 0; r < 4; ++r) {
        float m = S[nt2][0][r];
#pragma unroll
        for (int mt = 1; mt < 8; ++mt) m = fmaxf(m, S[nt2][mt][r]);
        mx[nt2][r] = m;
      }
#pragma unroll
    for (int d = 1; d < 16; d <<= 1)
#pragma unroll
      for (int nt2 = 0; nt2 < 2; ++nt2)
#pragma unroll
        for (int r = 0; r < 4; ++r)
          mx[nt2][r] = fmaxf(mx[nt2][r], __shfl_xor(mx[nt2][r], d));
    if (l15 == 0)
#pragma unroll
      for (int nt2 = 0; nt2 < 2; ++nt2)
#pragma unroll
        for (int r = 0; r < 4; ++r)
          smax[w][16*nt2 + 4*q + r] = mx[nt2][r];
  }
  __syncthreads();   // also fences last q-LDS read before P overwrites it
  {
#pragma unroll
    for (int nt2 = 0; nt2 < 2; ++nt2)
#pragma unroll
      for (int r = 0; r < 4; ++r) {
        int row = 16*nt2 + 4*q + r;
        float m = smax[0][row];
#pragma unroll
        for (int w2 = 1; w2 < 8; ++w2) m = fmaxf(m, smax[w2][row]);
        M[nt2][r] = m;
      }
    float sm[2][4] = {};
#pragma unroll
    for (int nt2 = 0; nt2 < 2; ++nt2)
#pragma unroll
      for (int mt = 0; mt < 8; ++mt)
#pragma unroll
        for (int r = 0; r < 4; ++r) {
          float p = __expf(S[nt2][mt][r] - M[nt2][r]);
          S[nt2][mt][r] = p;
          sm[nt2][r] += p;
        }
#pragma unroll
    for (int d = 1; d < 16; d <<= 1)
#pragma unroll
      for (int nt2 = 0; nt2 < 2; ++nt2)
#pragma unroll
        for (int r = 0; r < 4; ++r)
          sm[nt2][r] += __shfl_xor(sm[nt2][r], d);
    if (l15 == 0)
#pragma unroll
      for (int nt2 = 0; nt2 < 2; ++nt2)
#pragma unroll
        for (int r = 0; r < 4; ++r)
          ssum[w][16*nt2 + 4*q + r] = sm[nt2][r];
    // write unnormalized P (f16) to LDS
#pragma unroll
    for (int nt2 = 0; nt2 < 2; ++nt2)
#pragma unroll
      for (int mt = 0; mt < 8; ++mt)
#pragma unroll
        for (int r = 0; r < 4; ++r) {
          int row = 16*nt2 + 4*q + r;
          shp[row*PSTR + 128*w + 16*mt + l15] = (f16)S[nt2][mt][r];
        }
  }
  __syncthreads();
#pragma unroll
  for (int nt2 = 0; nt2 < 2; ++nt2)
#pragma unroll
    for (int r = 0; r < 4; ++r) {
      int row = 16*nt2 + 4*q + r;
      float s = ssum[0][row];
#pragma unroll
      for (int w2 = 1; w2 < 8; ++w2) s += ssum[w2][row];
      inv[nt2][r] = 1.0f / s;
    }

  // ---- Phase D: O[32][32 slice] = P . v^T ----
  f32x4 O[2][2] = {};
  {
    const f16* vbase[2];
#pragma unroll
    for (int ct = 0; ct < 2; ++ct)
      vbase[ct] = vC + (size_t)(b*CDIM + 32*w + 16*ct + l15)*NSUB + 8*q;
    for (int ks = 0; ks < 32; ++ks) {
      int m0 = ks * 32;
      f16x8 p0 = *(const f16x8*)(shp + (l15)*PSTR + m0 + 8*q);
      f16x8 p1 = *(const f16x8*)(shp + (16 + l15)*PSTR + m0 + 8*q);
      f16x8 v0 = ld8(vbase[0] + m0);
      f16x8 v1 = ld8(vbase[1] + m0);
      O[0][0] = mfma16(p0, v0, O[0][0]);
      O[0][1] = mfma16(p0, v1, O[0][1]);
      O[1][0] = mfma16(p1, v0, O[1][0]);
      O[1][1] = mfma16(p1, v1, O[1][1]);
    }
  }

  // ---- Phase E: out = gamma * O/rowsum + x ----
  float g = gamma_p[0];
#pragma unroll
  for (int nt2 = 0; nt2 < 2; ++nt2)
#pragma unroll
    for (int ct = 0; ct < 2; ++ct) {
      int c = 32*w + 16*ct + l15;
      size_t base = (size_t)(b*CDIM + c)*NPIX + n0 + 16*nt2 + 4*q;
      f32x4 xv = *(const f32x4*)(x + base);
      f32x4 ov;
#pragma unroll
      for (int r = 0; r < 4; ++r)
        ov[r] = g * (O[nt2][ct][r] * inv[nt2][r]) + xv[r];
      *(f32x4*)(out + base) = ov;
    }
}

extern "C" void kernel_launch(void* const* d_in, const int* in_sizes, int n_in,
                              void* d_out, int out_size, void* d_ws, size_t ws_size,
                              hipStream_t stream) {
  (void)in_sizes; (void)n_in; (void)out_size; (void)ws_size;
  const float* x     = (const float*)d_in[0];
  const float* Wq    = (const float*)d_in[1];
  const float* bq    = (const float*)d_in[2];
  const float* Wk    = (const float*)d_in[3];
  const float* bk    = (const float*)d_in[4];
  const float* Wv    = (const float*)d_in[5];
  const float* bv    = (const float*)d_in[6];
  const float* Ws    = (const float*)d_in[7];
  const float* bs    = (const float*)d_in[8];
  const float* gamma = (const float*)d_in[9];

  char* ws = (char*)d_ws;
  float* bk2 = (float*)(ws + 0);
  float* bv2 = (float*)(ws + 1024);
  f16* xT   = (f16*)(ws + 4096);
  f16* kT   = (f16*)(ws + 4096 + 37748736ull);
  f16* vC   = (f16*)(ws + 4096 + 37748736ull + 4194304ull);
  f16* WqH  = (f16*)(ws + 4096 + 37748736ull + 2*4194304ull);
  f16* Wk2H = (f16*)(ws + 4096 + 37748736ull + 2*4194304ull + 131072ull);
  f16* Wv2H = (f16*)(ws + 4096 + 37748736ull + 2*4194304ull + 2*131072ull);

  prep_weights<<<256, 256, 0, stream>>>(Wq, Wk, bk, Wv, bv, Ws, bs, WqH, Wk2H, Wv2H, bk2, bv2);
  transpose_x<<<dim3(CDIM/32, NPIX/32, NB), dim3(32, 8), 0, stream>>>(x, xT);
  compute_kv<<<dim3(NSUB/64, NB), 256, 0, stream>>>(xT, Wk2H, Wv2H, bk2, bv2, kT, vC);
  attention<<<NB * (NPIX/32), 512, 0, stream>>>(xT, WqH, bq, kT, vC, x, gamma, (float*)d_out);
}

// Round 2
// 396.017 us; speedup vs baseline: 1.0124x; 1.0124x over previous
//
#include <hip/hip_runtime.h>

typedef _Float16 f16;
typedef _Float16 f16x8 __attribute__((ext_vector_type(8)));
typedef float f32x4 __attribute__((ext_vector_type(4)));

#define CDIM 256
#define NPIX 9216
#define NSUB 1024
#define NB 8
#define QSTR 264
#define PSTR 1048

__device__ __forceinline__ f32x4 mfma16(f16x8 a, f16x8 b, f32x4 c) {
  return __builtin_amdgcn_mfma_f32_16x16x32_f16(a, b, c, 0, 0, 0);
}
__device__ __forceinline__ f16x8 ld8(const f16* p) { return *(const f16x8*)p; }

// ---------------- K1: fold weights, cast to f16 ----------------
__global__ void prep_weights(const float* __restrict__ Wq,
                             const float* __restrict__ Wk, const float* __restrict__ bk,
                             const float* __restrict__ Wv, const float* __restrict__ bv,
                             const float* __restrict__ Ws, const float* __restrict__ bs,
                             f16* __restrict__ WqH, f16* __restrict__ Wk2H, f16* __restrict__ Wv2H,
                             float* __restrict__ bk2, float* __restrict__ bv2) {
  int o = blockIdx.x, c = threadIdx.x;
  float ak = 0.f, av = 0.f;
  for (int i = 0; i < CDIM; ++i) {
    float w = Ws[o*CDIM + i];
    ak += w * Wk[i*CDIM + c];
    av += w * Wv[i*CDIM + c];
  }
  Wk2H[o*CDIM + c] = (f16)ak;
  Wv2H[o*CDIM + c] = (f16)av;
  WqH[o*CDIM + c]  = (f16)Wq[o*CDIM + c];
  if (c == 0) {
    float sk = 0.f, sv = 0.f;
    for (int i = 0; i < CDIM; ++i) { float w = Ws[o*CDIM + i]; sk += w*bk[i]; sv += w*bv[i]; }
    bk2[o] = sk + bs[o];
    bv2[o] = sv + bs[o];
  }
}

// ---------------- K2: x[b][c][n] f32 -> xT[b][n][c] f16 ----------------
__global__ void transpose_x(const float* __restrict__ x, f16* __restrict__ xT) {
  __shared__ f16 tile[32][34];
  int c0 = blockIdx.x * 32, n0 = blockIdx.y * 32, b = blockIdx.z;
  int tx = threadIdx.x, ty = threadIdx.y;
#pragma unroll
  for (int j = 0; j < 4; ++j) {
    int cl = ty + 8*j;
    tile[cl][tx] = (f16)x[(size_t)(b*CDIM + c0 + cl)*NPIX + n0 + tx];
  }
  __syncthreads();
#pragma unroll
  for (int j = 0; j < 4; ++j) {
    int nl = ty + 8*j;
    xT[(size_t)(b*NPIX + n0 + nl)*CDIM + c0 + tx] = tile[tx][nl];
  }
}

// ---------------- K3: kT[b][m][c], v[b][c][m] at subsampled pixels ----------------
__global__ __launch_bounds__(256) void compute_kv(
    const f16* __restrict__ xT, const f16* __restrict__ Wk2H, const f16* __restrict__ Wv2H,
    const float* __restrict__ bk2, const float* __restrict__ bv2,
    f16* __restrict__ kT, f16* __restrict__ vC) {
  int m064 = blockIdx.x * 64;
  int b = blockIdx.y;
  int tid = threadIdx.x;
  int w = tid >> 6, lane = tid & 63;
  int l15 = lane & 15, q = lane >> 4;

  const f16* xbase[4];
#pragma unroll
  for (int mt2 = 0; mt2 < 4; ++mt2) {
    int m = m064 + 16*mt2 + l15;
    int n = 288*(m >> 5) + 3*(m & 31);   // subsampled pixel index
    xbase[mt2] = xT + (size_t)(b*NPIX + n)*CDIM + 8*q;
  }
  const f16* kwb[4]; const f16* vwb[4];
#pragma unroll
  for (int t = 0; t < 4; ++t) {
    kwb[t] = Wk2H + (size_t)(64*w + 16*t + l15)*CDIM + 8*q;
    vwb[t] = Wv2H + (size_t)(64*w + 16*t + l15)*CDIM + 8*q;
  }
  f32x4 accK[4][4] = {};
  f32x4 accV[4][4] = {};
  for (int ks = 0; ks < 8; ++ks) {
    int c0 = ks * 32;
    f16x8 am[4], wk[4], wv[4];
#pragma unroll
    for (int t = 0; t < 4; ++t) {
      am[t] = ld8(xbase[t] + c0);
      wk[t] = ld8(kwb[t] + c0);
      wv[t] = ld8(vwb[t] + c0);
    }
#pragma unroll
    for (int mt2 = 0; mt2 < 4; ++mt2)
#pragma unroll
      for (int ot = 0; ot < 4; ++ot) {
        accK[mt2][ot] = mfma16(am[mt2], wk[ot], accK[mt2][ot]);   // D[m][o]
        accV[ot][mt2] = mfma16(wv[ot], am[mt2], accV[ot][mt2]);   // D[c][m]
      }
  }
#pragma unroll
  for (int mt2 = 0; mt2 < 4; ++mt2)
#pragma unroll
    for (int ot = 0; ot < 4; ++ot) {
      int o = 64*w + 16*ot + l15;
      float bo = bk2[o];
#pragma unroll
      for (int r = 0; r < 4; ++r) {
        int m = m064 + 16*mt2 + 4*q + r;
        kT[(size_t)(b*NSUB + m)*CDIM + o] = (f16)(accK[mt2][ot][r] + bo);
      }
    }
#pragma unroll
  for (int ct = 0; ct < 4; ++ct) {
    f32x4 bv4 = *(const f32x4*)(bv2 + 64*w + 16*ct + 4*q);
#pragma unroll
    for (int mt2 = 0; mt2 < 4; ++mt2) {
      int m = m064 + 16*mt2 + l15;
#pragma unroll
      for (int r = 0; r < 4; ++r) {
        int c = 64*w + 16*ct + 4*q + r;
        vC[(size_t)(b*CDIM + c)*NSUB + m] = (f16)(accV[ct][mt2][r] + bv4[r]);
      }
    }
  }
}

// ---------------- K4: fused attention ----------------
// __launch_bounds__(512,4): 4 waves/EU min -> VGPR cap 128 (occupancy is
// LDS-capped at 2 blocks/CU anyway); 64-VGPR default starved load ILP.
__global__ __launch_bounds__(512, 4) void attention(
    const f16* __restrict__ xT, const f16* __restrict__ WqH, const float* __restrict__ bq,
    const f16* __restrict__ kT, const f16* __restrict__ vC,
    const float* __restrict__ x, const float* __restrict__ gamma_p,
    float* __restrict__ out) {
  __shared__ f16 shp[32 * PSTR];          // P buffer; start aliased as q tile
  __shared__ float smax[8][32];
  __shared__ float ssum[8][32];
  f16* shq = shp;

  int bid = blockIdx.x;
  int b  = bid / (NPIX/32);
  int nt = bid % (NPIX/32);
  int n0 = nt * 32;
  int tid = threadIdx.x;
  int w = tid >> 6, lane = tid & 63;
  int l15 = lane & 15, q = lane >> 4;

  // K base for phase B (frag mt lives at kb + mt*16*CDIM + c0)
  const f16* kb = kT + (size_t)(b*NSUB + 128*w + l15)*CDIM + 8*q;
  // Preload K[ks=0] fragments early: independent of everything before phase B.
  f16x8 kc[8];
#pragma unroll
  for (int mt = 0; mt < 8; ++mt) kc[mt] = ld8(kb + mt*16*CDIM);

  // ---- Phase A: q tile [32][256] -> LDS (wave w computes cols 32w..32w+31) ----
  {
    f32x4 acc00 = {}, acc01 = {}, acc10 = {}, acc11 = {};
    const f16* xr0 = xT + (size_t)(b*NPIX + n0 + l15)*CDIM + 8*q;
    const f16* xr1 = xr0 + 16*CDIM;
    const f16* wr0 = WqH + (size_t)(32*w + l15)*CDIM + 8*q;
    const f16* wr1 = wr0 + 16*CDIM;
    f16x8 a0 = ld8(xr0), a1 = ld8(xr1), b0 = ld8(wr0), b1 = ld8(wr1);
#pragma unroll
    for (int ks = 0; ks < 8; ++ks) {
      f16x8 na0, na1, nb0, nb1;
      if (ks < 7) {
        int c1 = (ks + 1) * 32;
        na0 = ld8(xr0 + c1); na1 = ld8(xr1 + c1);
        nb0 = ld8(wr0 + c1); nb1 = ld8(wr1 + c1);
      }
      acc00 = mfma16(a0, b0, acc00);
      acc01 = mfma16(a0, b1, acc01);
      acc10 = mfma16(a1, b0, acc10);
      acc11 = mfma16(a1, b1, acc11);
      if (ks < 7) { a0 = na0; a1 = na1; b0 = nb0; b1 = nb1; }
    }
    f32x4 accs[2][2] = {{acc00, acc01}, {acc10, acc11}};
#pragma unroll
    for (int ot = 0; ot < 2; ++ot) {
      int o = 32*w + 16*ot + l15;
      float bo = bq[o];
#pragma unroll
      for (int nt2 = 0; nt2 < 2; ++nt2)
#pragma unroll
        for (int r = 0; r < 4; ++r) {
          int nl = 16*nt2 + 4*q + r;
          shq[nl*QSTR + o] = (f16)(accs[nt2][ot][r] + bo);
        }
    }
  }
  __syncthreads();

  // ---- Phase B: S[32][128 slice] = q . k, depth-2 pipelined ----
  f32x4 S[2][8] = {};
  {
#pragma unroll
    for (int ks = 0; ks < 8; ++ks) {
      int c0 = ks * 32;
      f16x8 a0 = *(const f16x8*)(shq + (l15)*QSTR + c0 + 8*q);
      f16x8 a1 = *(const f16x8*)(shq + (16 + l15)*QSTR + c0 + 8*q);
      f16x8 kn[8];
      if (ks < 7) {
#pragma unroll
        for (int mt = 0; mt < 4; ++mt) kn[mt] = ld8(kb + mt*16*CDIM + c0 + 32);
      }
#pragma unroll
      for (int mt = 0; mt < 4; ++mt) {
        S[0][mt] = mfma16(a0, kc[mt], S[0][mt]);
        S[1][mt] = mfma16(a1, kc[mt], S[1][mt]);
      }
      if (ks < 7) {
#pragma unroll
        for (int mt = 4; mt < 8; ++mt) kn[mt] = ld8(kb + mt*16*CDIM + c0 + 32);
      }
#pragma unroll
      for (int mt = 4; mt < 8; ++mt) {
        S[0][mt] = mfma16(a0, kc[mt], S[0][mt]);
        S[1][mt] = mfma16(a1, kc[mt], S[1][mt]);
      }
      if (ks < 7) {
#pragma unroll
        for (int mt = 0; mt < 8; ++mt) kc[mt] = kn[mt];
      }
    }
  }

  // Prefetch first two V key-blocks for phase D; live across the softmax barriers.
  const f16* vb0 = vC + (size_t)(b*CDIM + 32*w + l15)*NSUB + 8*q;
  const f16* vb1 = vb0 + 16*NSUB;
  f16x8 v00 = ld8(vb0),      v10 = ld8(vb1);
  f16x8 v01 = ld8(vb0 + 32), v11 = ld8(vb1 + 32);

  // ---- Phase C: softmax over m (rows owned per lane-quarter) ----
  float M[2][4], inv[2][4];
  {
    float mx[2][4];
#pragma unroll
    for (int nt2 = 0; nt2 < 2; ++nt2)
#pragma unroll
      for (int r = 0; r < 4; ++r) {
        float m = S[nt2][0][r];
#pragma unroll
        for (int mt = 1; mt < 8; ++mt) m = fmaxf(m, S[nt2][mt][r]);
        mx[nt2][r] = m;
      }
#pragma unroll
    for (int d = 1; d < 16; d <<= 1)
#pragma unroll
      for (int nt2 = 0; nt2 < 2; ++nt2)
#pragma unroll
        for (int r = 0; r < 4; ++r)
          mx[nt2][r] = fmaxf(mx[nt2][r], __shfl_xor(mx[nt2][r], d));
    if (l15 == 0)
#pragma unroll
      for (int nt2 = 0; nt2 < 2; ++nt2)
#pragma unroll
        for (int r = 0; r < 4; ++r)
          smax[w][16*nt2 + 4*q + r] = mx[nt2][r];
  }
  __syncthreads();   // also fences last q-LDS read before P overwrites it
  {
#pragma unroll
    for (int nt2 = 0; nt2 < 2; ++nt2)
#pragma unroll
      for (int r = 0; r < 4; ++r) {
        int row = 16*nt2 + 4*q + r;
        float m = smax[0][row];
#pragma unroll
        for (int w2 = 1; w2 < 8; ++w2) m = fmaxf(m, smax[w2][row]);
        M[nt2][r] = m;
      }
    float sm[2][4] = {};
#pragma unroll
    for (int nt2 = 0; nt2 < 2; ++nt2)
#pragma unroll
      for (int mt = 0; mt < 8; ++mt)
#pragma unroll
        for (int r = 0; r < 4; ++r) {
          float p = __expf(S[nt2][mt][r] - M[nt2][r]);
          S[nt2][mt][r] = p;
          sm[nt2][r] += p;
        }
#pragma unroll
    for (int d = 1; d < 16; d <<= 1)
#pragma unroll
      for (int nt2 = 0; nt2 < 2; ++nt2)
#pragma unroll
        for (int r = 0; r < 4; ++r)
          sm[nt2][r] += __shfl_xor(sm[nt2][r], d);
    if (l15 == 0)
#pragma unroll
      for (int nt2 = 0; nt2 < 2; ++nt2)
#pragma unroll
        for (int r = 0; r < 4; ++r)
          ssum[w][16*nt2 + 4*q + r] = sm[nt2][r];
    // write unnormalized P (f16) to LDS
#pragma unroll
    for (int nt2 = 0; nt2 < 2; ++nt2)
#pragma unroll
      for (int mt = 0; mt < 8; ++mt)
#pragma unroll
        for (int r = 0; r < 4; ++r) {
          int row = 16*nt2 + 4*q + r;
          shp[row*PSTR + 128*w + 16*mt + l15] = (f16)S[nt2][mt][r];
        }
  }
  __syncthreads();
#pragma unroll
  for (int nt2 = 0; nt2 < 2; ++nt2)
#pragma unroll
    for (int r = 0; r < 4; ++r) {
      int row = 16*nt2 + 4*q + r;
      float s = ssum[0][row];
#pragma unroll
      for (int w2 = 1; w2 < 8; ++w2) s += ssum[w2][row];
      inv[nt2][r] = 1.0f / s;
    }

  // ---- Phase D: O[32][32 slice] = P . v^T, unroll-2 + V double-buffer ----
  f32x4 O00 = {}, O01 = {}, O10 = {}, O11 = {};
  {
#pragma unroll
    for (int kb2 = 0; kb2 < 16; ++kb2) {
      int m0 = kb2 * 64;
      f16x8 nv00, nv10, nv01, nv11;
      if (kb2 < 15) {
        nv00 = ld8(vb0 + m0 + 64); nv10 = ld8(vb1 + m0 + 64);
        nv01 = ld8(vb0 + m0 + 96); nv11 = ld8(vb1 + m0 + 96);
      }
      f16x8 p00 = *(const f16x8*)(shp + (l15)*PSTR + m0 + 8*q);
      f16x8 p10 = *(const f16x8*)(shp + (16 + l15)*PSTR + m0 + 8*q);
      O00 = mfma16(p00, v00, O00);
      O01 = mfma16(p00, v10, O01);
      O10 = mfma16(p10, v00, O10);
      O11 = mfma16(p10, v10, O11);
      f16x8 p01 = *(const f16x8*)(shp + (l15)*PSTR + m0 + 32 + 8*q);
      f16x8 p11 = *(const f16x8*)(shp + (16 + l15)*PSTR + m0 + 32 + 8*q);
      O00 = mfma16(p01, v01, O00);
      O01 = mfma16(p01, v11, O01);
      O10 = mfma16(p11, v01, O10);
      O11 = mfma16(p11, v11, O11);
      if (kb2 < 15) { v00 = nv00; v10 = nv10; v01 = nv01; v11 = nv11; }
    }
  }

  // ---- Phase E: out = gamma * O/rowsum + x ----
  float g = gamma_p[0];
  f32x4 O[2][2] = {{O00, O01}, {O10, O11}};
#pragma unroll
  for (int nt2 = 0; nt2 < 2; ++nt2)
#pragma unroll
    for (int ct = 0; ct < 2; ++ct) {
      int c = 32*w + 16*ct + l15;
      size_t base = (size_t)(b*CDIM + c)*NPIX + n0 + 16*nt2 + 4*q;
      f32x4 xv = *(const f32x4*)(x + base);
      f32x4 ov;
#pragma unroll
      for (int r = 0; r < 4; ++r)
        ov[r] = g * (O[nt2][ct][r] * inv[nt2][r]) + xv[r];
      *(f32x4*)(out + base) = ov;
    }
}

extern "C" void kernel_launch(void* const* d_in, const int* in_sizes, int n_in,
                              void* d_out, int out_size, void* d_ws, size_t ws_size,
                              hipStream_t stream) {
  (void)in_sizes; (void)n_in; (void)out_size; (void)ws_size;
  const float* x     = (const float*)d_in[0];
  const float* Wq    = (const float*)d_in[1];
  const float* bq    = (const float*)d_in[2];
  const float* Wk    = (const float*)d_in[3];
  const float* bk    = (const float*)d_in[4];
  const float* Wv    = (const float*)d_in[5];
  const float* bv    = (const float*)d_in[6];
  const float* Ws    = (const float*)d_in[7];
  const float* bs    = (const float*)d_in[8];
  const float* gamma = (const float*)d_in[9];

  char* ws = (char*)d_ws;
  float* bk2 = (float*)(ws + 0);
  float* bv2 = (float*)(ws + 1024);
  f16* xT   = (f16*)(ws + 4096);
  f16* kT   = (f16*)(ws + 4096 + 37748736ull);
  f16* vC   = (f16*)(ws + 4096 + 37748736ull + 4194304ull);
  f16* WqH  = (f16*)(ws + 4096 + 37748736ull + 2*4194304ull);
  f16* Wk2H = (f16*)(ws + 4096 + 37748736ull + 2*4194304ull + 131072ull);
  f16* Wv2H = (f16*)(ws + 4096 + 37748736ull + 2*4194304ull + 2*131072ull);

  prep_weights<<<256, 256, 0, stream>>>(Wq, Wk, bk, Wv, bv, Ws, bs, WqH, Wk2H, Wv2H, bk2, bv2);
  transpose_x<<<dim3(CDIM/32, NPIX/32, NB), dim3(32, 8), 0, stream>>>(x, xT);
  compute_kv<<<dim3(NSUB/64, NB), 256, 0, stream>>>(xT, Wk2H, Wv2H, bk2, bv2, kT, vC);
  attention<<<NB * (NPIX/32), 512, 0, stream>>>(xT, WqH, bq, kT, vC, x, gamma, (float*)d_out);
}

// Round 3
// 276.954 us; speedup vs baseline: 1.4477x; 1.4299x over previous
//
#include <hip/hip_runtime.h>

typedef _Float16 f16;
typedef _Float16 f16x8 __attribute__((ext_vector_type(8)));
typedef float f32x4 __attribute__((ext_vector_type(4)));

#define CDIM 256
#define NPIX 9216
#define NSUB 1024
#define NB 8
#define QSTRB 528   // q LDS row stride in bytes (264 f16)

__device__ __forceinline__ f32x4 mfma16(f16x8 a, f16x8 b, f32x4 c) {
  return __builtin_amdgcn_mfma_f32_16x16x32_f16(a, b, c, 0, 0, 0);
}
__device__ __forceinline__ f16x8 ld8(const f16* p) { return *(const f16x8*)p; }

__device__ __forceinline__ void stage16(const void* g, void* l) {
  __builtin_amdgcn_global_load_lds((const __attribute__((address_space(1))) unsigned int*)g,
                                   (__attribute__((address_space(3))) unsigned int*)l, 16, 0, 0);
}
#define S_BARRIER() do { asm volatile("" ::: "memory"); __builtin_amdgcn_s_barrier(); asm volatile("" ::: "memory"); } while (0)
#define WAIT_VM(N) do { asm volatile("s_waitcnt vmcnt(" #N ")" ::: "memory"); __builtin_amdgcn_sched_barrier(0); } while (0)
#define WAIT_LGKM0() do { asm volatile("s_waitcnt lgkmcnt(0)" ::: "memory"); __builtin_amdgcn_sched_barrier(0); } while (0)

// ---------------- K1: fold weights, cast to f16 ----------------
__global__ void prep_weights(const float* __restrict__ Wq,
                             const float* __restrict__ Wk, const float* __restrict__ bk,
                             const float* __restrict__ Wv, const float* __restrict__ bv,
                             const float* __restrict__ Ws, const float* __restrict__ bs,
                             f16* __restrict__ WqH, f16* __restrict__ Wk2H, f16* __restrict__ Wv2H,
                             float* __restrict__ bk2, float* __restrict__ bv2) {
  int o = blockIdx.x, c = threadIdx.x;
  float ak = 0.f, av = 0.f;
  for (int i = 0; i < CDIM; ++i) {
    float w = Ws[o*CDIM + i];
    ak += w * Wk[i*CDIM + c];
    av += w * Wv[i*CDIM + c];
  }
  Wk2H[o*CDIM + c] = (f16)ak;
  Wv2H[o*CDIM + c] = (f16)av;
  WqH[o*CDIM + c]  = (f16)Wq[o*CDIM + c];
  if (c == 0) {
    float sk = 0.f, sv = 0.f;
    for (int i = 0; i < CDIM; ++i) { float w = Ws[o*CDIM + i]; sk += w*bk[i]; sv += w*bv[i]; }
    bk2[o] = sk + bs[o];
    bv2[o] = sv + bs[o];
  }
}

// ---------------- K2: x[b][c][n] f32 -> xT (swizzled [b][n][c] f16) ----------------
// xT byte layout: row n = 512B; 16B unit u (= c>>3) stored at u ^ (n&7).
__global__ void transpose_x(const float* __restrict__ x, char* __restrict__ xT) {
  __shared__ f16 tile[32][34];   // [c][n]
  int c0 = blockIdx.x * 32, n0 = blockIdx.y * 32, b = blockIdx.z;
  int tx = threadIdx.x, ty = threadIdx.y;
#pragma unroll
  for (int j = 0; j < 4; ++j) {
    int cl = ty + 8*j;
    tile[cl][tx] = (f16)x[(size_t)(b*CDIM + c0 + cl)*NPIX + n0 + tx];
  }
  __syncthreads();
  int tid = ty*32 + tx;
  if (tid < 128) {
    int nl = tid >> 2, u = tid & 3;
    int n = n0 + nl;
    int cu = (c0 >> 3) + u;          // global 16B-unit index within the 512B row
    f16x8 v;
#pragma unroll
    for (int e = 0; e < 8; ++e) v[e] = tile[8*u + e][nl];
    size_t byte = (size_t)(b*NPIX + n)*512 + (size_t)((cu ^ (n & 7)) << 4);
    *(f16x8*)(xT + byte) = v;
  }
}

// ---------------- K3: K/V at subsampled pixels -> blocked swizzled layouts ----------------
// kB[b][ksB(8)][m(1024)][c(32)] f16; per (b,ksB) 64KB; swizzle: unit u=((m&1)<<2)|(ci>>3),
//   stored at u ^ ((m>>1)&7) within the 128B m-pair.
// vB[b][ch(16)][c(256)][mi(64)] f16; per (b,ch) 32KB; unit (mi>>3) stored ^ (c&7).
__global__ __launch_bounds__(256) void compute_kv(
    const char* __restrict__ xT, const f16* __restrict__ Wk2H, const f16* __restrict__ Wv2H,
    const float* __restrict__ bk2, const float* __restrict__ bv2,
    char* __restrict__ kB, char* __restrict__ vB) {
  int m0 = blockIdx.x * 32;
  int b = blockIdx.y;
  int tid = threadIdx.x;
  int w = tid >> 6, lane = tid & 63, l15 = lane & 15, q = lane >> 4;

  const char* xrow[2]; int xn7[2];
#pragma unroll
  for (int mt2 = 0; mt2 < 2; ++mt2) {
    int m = m0 + 16*mt2 + l15;
    int n = 288*(m >> 5) + 3*(m & 31);   // subsampled pixel index
    xrow[mt2] = xT + (size_t)(b*NPIX + n)*512;
    xn7[mt2] = n & 7;
  }
  const f16 *kwb[4], *vwb[4];
#pragma unroll
  for (int t = 0; t < 4; ++t) {
    kwb[t] = Wk2H + (size_t)(64*w + 16*t + l15)*CDIM + 8*q;
    vwb[t] = Wv2H + (size_t)(64*w + 16*t + l15)*CDIM + 8*q;
  }
  f32x4 accK[2][4] = {};
  f32x4 accV[4][2] = {};
  for (int ks = 0; ks < 8; ++ks) {
    f16x8 am[2], wk[4], wv[4];
#pragma unroll
    for (int mt2 = 0; mt2 < 2; ++mt2)
      am[mt2] = *(const f16x8*)(xrow[mt2] + (((q + 4*ks) ^ xn7[mt2]) << 4));
#pragma unroll
    for (int t = 0; t < 4; ++t) { wk[t] = ld8(kwb[t] + 32*ks); wv[t] = ld8(vwb[t] + 32*ks); }
#pragma unroll
    for (int mt2 = 0; mt2 < 2; ++mt2)
#pragma unroll
      for (int ot = 0; ot < 4; ++ot) {
        accK[mt2][ot] = mfma16(am[mt2], wk[ot], accK[mt2][ot]);   // D[m][c]
        accV[ot][mt2] = mfma16(wv[ot], am[mt2], accV[ot][mt2]);   // D[c][m]
      }
  }
  // write kB
#pragma unroll
  for (int mt2 = 0; mt2 < 2; ++mt2)
#pragma unroll
    for (int ot = 0; ot < 4; ++ot) {
      int cg = 64*w + 16*ot + l15;
      float bo = bk2[cg];
      int ksB = cg >> 5, ci = cg & 31;
#pragma unroll
      for (int r = 0; r < 4; ++r) {
        int m = m0 + 16*mt2 + 4*q + r;
        int u = (((m & 1) << 2) | (ci >> 3)) ^ ((m >> 1) & 7);
        size_t off = (size_t)b*524288 + (size_t)ksB*65536 + (size_t)(m >> 1)*128 + (u << 4) + ((ci & 7) << 1);
        *(f16*)(kB + off) = (f16)(accK[mt2][ot][r] + bo);
      }
    }
  // write vB
#pragma unroll
  for (int ct = 0; ct < 4; ++ct) {
    f32x4 bv4 = *(const f32x4*)(bv2 + 64*w + 16*ct + 4*q);
#pragma unroll
    for (int mt2 = 0; mt2 < 2; ++mt2) {
      int m = m0 + 16*mt2 + l15;
      int ch = m >> 6, mi = m & 63;
#pragma unroll
      for (int r = 0; r < 4; ++r) {
        int cg = 64*w + 16*ct + 4*q + r;
        int u = (mi >> 3) ^ (cg & 7);
        size_t off = (size_t)b*524288 + (size_t)ch*32768 + (size_t)cg*128 + (u << 4) + ((mi & 7) << 1);
        *(f16*)(vB + off) = (f16)(accV[ct][mt2][r] + bv4[r]);
      }
    }
  }
}

// ---------------- K4: fused attention, 64 q-rows/block, LDS-staged K/V ----------------
__global__ __launch_bounds__(512, 2) void attention(
    const char* __restrict__ xT, const f16* __restrict__ WqH, const float* __restrict__ bq,
    const char* __restrict__ kB, const char* __restrict__ vB,
    const float* __restrict__ x, const float* __restrict__ gamma_p,
    float* __restrict__ out) {
  __shared__ char bufKV[65536];    // 2 x 32KB chunk double-buffer (xT tile / K / V)
  __shared__ char bufQP[33792];    // q[64][264] f16, later P chunk dbuf 2 x 8KB
  __shared__ float smax[8][64];
  __shared__ float ssum[8][64];

  int bid = blockIdx.x;
  int b = bid / 144, ntb = bid % 144;
  int n0 = ntb * 64;
  int tid = threadIdx.x;
  int w = tid >> 6, lane = tid & 63, l15 = lane & 15, q = lane >> 4;

  const char* xTt = xT + (size_t)(b*NPIX + n0)*512;
  const char* kBb = kB + (size_t)b*524288;
  const char* vBb = vB + (size_t)b*524288;

  // prologue: stage xT tile (32KB) -> buf0, K chunk0 -> buf1
  {
    int o = tid * 16;
#pragma unroll
    for (int r = 0; r < 4; ++r) stage16(xTt + o + r*8192, bufKV + o + r*8192);
#pragma unroll
    for (int r = 0; r < 4; ++r) stage16(kBb + o + r*8192, bufKV + 32768 + o + r*8192);
  }

  // ---- Phase A: q = x.Wq^T + bq -> bufQP (wave w computes cols 32w..32w+31) ----
  {
    f16x8 wb[2][8];
    const f16* wr0 = WqH + (size_t)(32*w + l15)*CDIM + 8*q;
    const f16* wr1 = wr0 + 16*CDIM;
#pragma unroll
    for (int ks = 0; ks < 8; ++ks) { wb[0][ks] = ld8(wr0 + 32*ks); wb[1][ks] = ld8(wr1 + 32*ks); }
    float bo0 = bq[32*w + l15], bo1 = bq[32*w + 16 + l15];
    WAIT_VM(0);          // xT tile staged (also drains K0; one-time cost)
    S_BARRIER();
    f32x4 acc[4][2] = {};
#pragma unroll
    for (int ks = 0; ks < 8; ++ks)
#pragma unroll
      for (int nt = 0; nt < 4; ++nt) {
        int n = 16*nt + l15;
        f16x8 a = *(const f16x8*)(bufKV + n*512 + (((q + 4*ks) ^ (n & 7)) << 4));
        acc[nt][0] = mfma16(a, wb[0][ks], acc[nt][0]);
        acc[nt][1] = mfma16(a, wb[1][ks], acc[nt][1]);
      }
#pragma unroll
    for (int nt = 0; nt < 4; ++nt)
#pragma unroll
      for (int ot = 0; ot < 2; ++ot) {
        int o = 32*w + 16*ot + l15;
        float bo = ot ? bo1 : bo0;
#pragma unroll
        for (int r = 0; r < 4; ++r) {
          int n = 16*nt + 4*q + r;
          *(f16*)(bufQP + n*QSTRB + o*2) = (f16)(acc[nt][ot][r] + bo);
        }
      }
    WAIT_LGKM0();
    S_BARRIER();
  }

  // ---- Phase B: S = q.K^T over 16 chunks (ks 0..7 x half 0..1), K staged dbuf ----
  f32x4 S[4][8] = {};
#pragma unroll
  for (int j = 0; j < 16; ++j) {
    int cur = (j + 1) & 1;               // chunk j lives in buf[(j+1)&1]
    if (j < 15) {
      int j1 = j + 1;
      const char* src = kBb + (size_t)(j1 >> 1)*65536 + (size_t)(j1 & 1)*32768;
      int o = tid * 16;
#pragma unroll
      for (int r = 0; r < 4; ++r) stage16(src + o + r*8192, bufKV + (cur^1)*32768 + o + r*8192);
    }
    if (j < 15) { WAIT_VM(4); } else { WAIT_VM(0); }
    S_BARRIER();
    int ks = j >> 1, h = j & 1;
    const char* kc = bufKV + cur*32768;
    f16x8 a[4], bk[4];
#pragma unroll
    for (int nt = 0; nt < 4; ++nt) {
      int n = 16*nt + l15;
      a[nt] = *(const f16x8*)(bufQP + n*QSTRB + 16*q + 64*ks);
    }
#pragma unroll
    for (int mt = 0; mt < 4; ++mt) {
      int ml = 64*w + 16*mt + l15;
      int u = (((ml & 1) << 2) | q) ^ ((ml >> 1) & 7);
      bk[mt] = *(const f16x8*)(kc + (ml >> 1)*128 + (u << 4));
    }
#pragma unroll
    for (int nt = 0; nt < 4; ++nt)
#pragma unroll
      for (int mt = 0; mt < 4; ++mt)
        S[nt][h*4 + mt] = mfma16(a[nt], bk[mt], S[nt][h*4 + mt]);
    S_BARRIER();
  }

  // stage V chunk0 -> buf1 early (hidden under softmax)
  {
    int o = tid * 16;
#pragma unroll
    for (int r = 0; r < 4; ++r) stage16(vBb + o + r*8192, bufKV + 32768 + o + r*8192);
  }

  // ---- Phase C: softmax (lane owns n = 16nt+4q+r, m = 512h+64w+16mt+l15) ----
  {
    float M[4][4];
#pragma unroll
    for (int nt = 0; nt < 4; ++nt)
#pragma unroll
      for (int r = 0; r < 4; ++r) {
        float m = S[nt][0][r];
#pragma unroll
        for (int ms = 1; ms < 8; ++ms) m = fmaxf(m, S[nt][ms][r]);
#pragma unroll
        for (int d = 1; d < 16; d <<= 1) m = fmaxf(m, __shfl_xor(m, d));
        M[nt][r] = m;
      }
    if (l15 == 0)
#pragma unroll
      for (int nt = 0; nt < 4; ++nt)
#pragma unroll
        for (int r = 0; r < 4; ++r) smax[w][16*nt + 4*q + r] = M[nt][r];
    WAIT_LGKM0();
    S_BARRIER();
#pragma unroll
    for (int nt = 0; nt < 4; ++nt)
#pragma unroll
      for (int r = 0; r < 4; ++r) {
        int n = 16*nt + 4*q + r;
        float m = smax[0][n];
#pragma unroll
        for (int w2 = 1; w2 < 8; ++w2) m = fmaxf(m, smax[w2][n]);
        M[nt][r] = m;
      }
    float sm[4][4] = {};
#pragma unroll
    for (int nt = 0; nt < 4; ++nt)
#pragma unroll
      for (int ms = 0; ms < 8; ++ms)
#pragma unroll
        for (int r = 0; r < 4; ++r) {
          float p = __expf(S[nt][ms][r] - M[nt][r]);
          S[nt][ms][r] = p;
          sm[nt][r] += p;
        }
#pragma unroll
    for (int nt = 0; nt < 4; ++nt)
#pragma unroll
      for (int r = 0; r < 4; ++r)
#pragma unroll
        for (int d = 1; d < 16; d <<= 1) sm[nt][r] += __shfl_xor(sm[nt][r], d);
    if (l15 == 0)
#pragma unroll
      for (int nt = 0; nt < 4; ++nt)
#pragma unroll
        for (int r = 0; r < 4; ++r) ssum[w][16*nt + 4*q + r] = sm[nt][r];
    WAIT_LGKM0();
    S_BARRIER();
    // fold 1/rowsum into S (P becomes normalized)
#pragma unroll
    for (int nt = 0; nt < 4; ++nt)
#pragma unroll
      for (int r = 0; r < 4; ++r) {
        int n = 16*nt + 4*q + r;
        float s = ssum[0][n];
#pragma unroll
        for (int w2 = 1; w2 < 8; ++w2) s += ssum[w2][n];
        float iv = 1.0f / s;
#pragma unroll
        for (int ms = 0; ms < 8; ++ms) S[nt][ms][r] *= iv;
      }
  }

  // P-chunk writer: chunk ch (64 keys) owned by wave ch&7, S slot group (ch>>3)*4
  auto writeP = [&](int ch, char* dst) {
    if (w == (ch & 7)) {
      int msb = (ch >> 3) * 4;
#pragma unroll
      for (int nt = 0; nt < 4; ++nt)
#pragma unroll
        for (int mt = 0; mt < 4; ++mt)
#pragma unroll
          for (int r = 0; r < 4; ++r) {
            int n = 16*nt + 4*q + r;
            int mi = 16*mt + l15;
            *(f16*)(dst + n*128 + (((mi >> 3) ^ (n & 7)) << 4) + ((mi & 7) << 1)) = (f16)S[nt][msb + mt][r];
          }
    }
  };

  writeP(0, bufQP);          // P0 -> pbuf0 (q is dead; region reused)
  WAIT_LGKM0();
  S_BARRIER();

  // ---- Phase D: O += P.V over 16 V-chunks (64 keys each), V staged dbuf ----
  f32x4 O[4][2] = {};
#pragma unroll
  for (int ch = 0; ch < 16; ++ch) {
    int cur = (ch + 1) & 1;
    if (ch < 15) {
      const char* src = vBb + (size_t)(ch + 1)*32768;
      int o = tid * 16;
#pragma unroll
      for (int r = 0; r < 4; ++r) stage16(src + o + r*8192, bufKV + (cur^1)*32768 + o + r*8192);
    }
    if (ch < 15) { WAIT_VM(4); } else { WAIT_VM(0); }
    S_BARRIER();
    const char* vc = bufKV + cur*32768;
    const char* pc = bufQP + (ch & 1)*8192;
    f16x8 pa[4][2], vf[2][2];
#pragma unroll
    for (int nt = 0; nt < 4; ++nt)
#pragma unroll
      for (int k2 = 0; k2 < 2; ++k2) {
        int n = 16*nt + l15;
        pa[nt][k2] = *(const f16x8*)(pc + n*128 + ((((4*k2 + q) ^ (n & 7)) << 4)));
      }
#pragma unroll
    for (int ct = 0; ct < 2; ++ct)
#pragma unroll
      for (int k2 = 0; k2 < 2; ++k2) {
        int c = 32*w + 16*ct + l15;
        vf[ct][k2] = *(const f16x8*)(vc + c*128 + ((((4*k2 + q) ^ (c & 7)) << 4)));
      }
#pragma unroll
    for (int nt = 0; nt < 4; ++nt)
#pragma unroll
      for (int k2 = 0; k2 < 2; ++k2)
#pragma unroll
        for (int ct = 0; ct < 2; ++ct)
          O[nt][ct] = mfma16(pa[nt][k2], vf[ct][k2], O[nt][ct]);
    if (ch < 15) writeP(ch + 1, bufQP + ((ch + 1) & 1)*8192);
    WAIT_LGKM0();
    S_BARRIER();
  }

  // ---- Phase E: out = gamma*O + x ----
  float g = gamma_p[0];
#pragma unroll
  for (int nt = 0; nt < 4; ++nt)
#pragma unroll
    for (int ct = 0; ct < 2; ++ct) {
      int c = 32*w + 16*ct + l15;
      size_t base = (size_t)(b*CDIM + c)*NPIX + n0 + 16*nt + 4*q;
      f32x4 xv = *(const f32x4*)(x + base);
      f32x4 ov;
#pragma unroll
      for (int r = 0; r < 4; ++r) ov[r] = g * O[nt][ct][r] + xv[r];
      *(f32x4*)(out + base) = ov;
    }
}

extern "C" void kernel_launch(void* const* d_in, const int* in_sizes, int n_in,
                              void* d_out, int out_size, void* d_ws, size_t ws_size,
                              hipStream_t stream) {
  (void)in_sizes; (void)n_in; (void)out_size; (void)ws_size;
  const float* x     = (const float*)d_in[0];
  const float* Wq    = (const float*)d_in[1];
  const float* bq    = (const float*)d_in[2];
  const float* Wk    = (const float*)d_in[3];
  const float* bk    = (const float*)d_in[4];
  const float* Wv    = (const float*)d_in[5];
  const float* bv    = (const float*)d_in[6];
  const float* Ws    = (const float*)d_in[7];
  const float* bs    = (const float*)d_in[8];
  const float* gamma = (const float*)d_in[9];

  char* ws = (char*)d_ws;
  float* bk2 = (float*)(ws);
  float* bv2 = (float*)(ws + 1024);
  char* xT   = ws + 4096;
  char* kB   = ws + 4096 + 37748736;
  char* vB   = kB + 4194304;
  f16* WqH   = (f16*)(vB + 4194304);
  f16* Wk2H  = WqH + 65536;
  f16* Wv2H  = Wk2H + 65536;

  prep_weights<<<256, 256, 0, stream>>>(Wq, Wk, bk, Wv, bv, Ws, bs, WqH, Wk2H, Wv2H, bk2, bv2);
  transpose_x<<<dim3(8, 288, 8), dim3(32, 8), 0, stream>>>(x, xT);
  compute_kv<<<dim3(32, 8), 256, 0, stream>>>(xT, Wk2H, Wv2H, bk2, bv2, kB, vB);
  attention<<<1152, 512, 0, stream>>>(xT, WqH, bq, kB, vB, x, gamma, (float*)d_out);
}